// Round 3
// baseline (3788.705 us; speedup 1.0000x reference)
//
#include <hip/hip_runtime.h>
#include <hip/hip_bf16.h>
#include <math.h>

#define NB 2
#define LL 2048
#define DD 768
#define DI 1536
#define DS 16
#define MM (NB*LL)   // 4096

typedef __hip_bfloat16 bf16;
typedef __attribute__((ext_vector_type(8))) __bf16 bf16x8;
typedef __attribute__((ext_vector_type(4))) float f32x4;

__device__ __forceinline__ float b2f(bf16 v){ return __bfloat162float(v); }
__device__ __forceinline__ bf16 f2b(float v){ return __float2bfloat16(v); }

__device__ __forceinline__ void async_cp16(const bf16* g, __bf16* l) {
  __builtin_amdgcn_global_load_lds((const __attribute__((address_space(1))) void*)g,
                                   (__attribute__((address_space(3))) void*)l, 16, 0, 0);
}

#define ACT_NONE 0
#define ACT_SOFTPLUS 1
#define ACT_GELU 2

// C[M,N] = A[M,K] @ B[N,K]^T  (+bias fp32) ->act (+addp fp32)
// flipA: read A row (row^2047)   flipstore: write C row (row^2047)
__global__ void gemm_kernel(const bf16* __restrict__ A, int lda,
                            const bf16* __restrict__ B, int ldb,
                            void* __restrict__ C, int ldc,
                            int N, int K,
                            const float* __restrict__ bias,
                            const float* __restrict__ addp, int ldadd,
                            int act, int f32out, int flipstore, int flipA)
{
  __shared__ __bf16 As[128*32];
  __shared__ __bf16 Bs[128*32];
  const int tid  = threadIdx.x;
  const int lane = tid & 63, wave = tid >> 6;
  const int m0 = blockIdx.x * 128, n0 = blockIdx.y * 128;
  const int wm = wave & 1, wn = wave >> 1;

  // staging: each wave stages 32 rows of A and 32 rows of B (16 rows per issue)
  const int srow = wave*32 + (lane >> 2);
  const int scol = (lane & 3) * 8;
  int ar0 = m0 + srow, ar1 = m0 + srow + 16;
  if (flipA) { ar0 ^= 2047; ar1 ^= 2047; }
  const bf16* Ag0 = A + (size_t)ar0 * lda + scol;
  const bf16* Ag1 = A + (size_t)ar1 * lda + scol;
  int br0 = n0 + srow;      if (br0 > N-1) br0 = N-1;
  int br1 = n0 + srow + 16; if (br1 > N-1) br1 = N-1;
  const bf16* Bg0 = B + (size_t)br0 * ldb + scol;
  const bf16* Bg1 = B + (size_t)br1 * ldb + scol;
  __bf16* AsW0 = &As[(wave*32     )*32];
  __bf16* AsW1 = &As[(wave*32 + 16)*32];
  __bf16* BsW0 = &Bs[(wave*32     )*32];
  __bf16* BsW1 = &Bs[(wave*32 + 16)*32];

  f32x4 acc[4][4] = {};
  const int arow = wm*64 + (lane & 15);
  const int brow = wn*64 + (lane & 15);
  const int kgrp = (lane >> 4) * 8;

  for (int kb = 0; kb < K; kb += 32) {
    __syncthreads();
    async_cp16(Ag0 + kb, AsW0);
    async_cp16(Ag1 + kb, AsW1);
    async_cp16(Bg0 + kb, BsW0);
    async_cp16(Bg1 + kb, BsW1);
    __syncthreads();
    bf16x8 af[4], bfr[4];
    #pragma unroll
    for (int i = 0; i < 4; i++) af[i]  = *(const bf16x8*)&As[(arow + i*16)*32 + kgrp];
    #pragma unroll
    for (int j = 0; j < 4; j++) bfr[j] = *(const bf16x8*)&Bs[(brow + j*16)*32 + kgrp];
    #pragma unroll
    for (int i = 0; i < 4; i++)
      #pragma unroll
      for (int j = 0; j < 4; j++)
        acc[i][j] = __builtin_amdgcn_mfma_f32_16x16x32_bf16(af[i], bfr[j], acc[i][j], 0, 0, 0);
  }

  bf16*  Cb = (bf16*)C;
  float* Cf = (float*)C;
  #pragma unroll
  for (int i = 0; i < 4; i++) {
    int rbase = m0 + wm*64 + i*16 + (lane >> 4)*4;
    #pragma unroll
    for (int j = 0; j < 4; j++) {
      int col = n0 + wn*64 + j*16 + (lane & 15);
      if (col >= N) continue;
      float bv = bias ? bias[col] : 0.f;
      #pragma unroll
      for (int r = 0; r < 4; r++) {
        int row = rbase + r;
        float v = acc[i][j][r] + bv;
        if (act == ACT_SOFTPLUS) {
          v = (v > 15.f) ? v : log1pf(__expf(v));
        } else if (act == ACT_GELU) {
          float u = 0.7978845608028654f * (v + 0.044715f*v*v*v);
          v = 0.5f * v * (1.f + tanhf(u));
        }
        if (addp) v += addp[(size_t)row * ldadd + col];
        int rs = flipstore ? (row ^ 2047) : row;
        if (f32out) Cf[(size_t)rs * ldc + col] = v;
        else        Cb[(size_t)rs * ldc + col] = f2b(v);
      }
    }
  }
}

// LayerNorm over D=768; fp32 in, bf16 out
__global__ void ln_kernel(const float* __restrict__ x, const float* __restrict__ g,
                          const float* __restrict__ b, bf16* __restrict__ out)
{
  const int row = blockIdx.x;     // 0..4095
  const int tid = threadIdx.x;    // 256
  const float* xr = x + (size_t)row * DD;
  float v[3], s = 0.f, s2 = 0.f;
  #pragma unroll
  for (int i = 0; i < 3; i++) {
    float f = xr[tid + i*256];
    v[i] = f; s += f; s2 += f*f;
  }
  #pragma unroll
  for (int o = 32; o > 0; o >>= 1) { s += __shfl_down(s, o, 64); s2 += __shfl_down(s2, o, 64); }
  __shared__ float ps[4], ps2[4];
  int wave = tid >> 6;
  if ((tid & 63) == 0) { ps[wave] = s; ps2[wave] = s2; }
  __syncthreads();
  s = ps[0]+ps[1]+ps[2]+ps[3]; s2 = ps2[0]+ps2[1]+ps2[2]+ps2[3];
  float mu = s * (1.f/DD);
  float var = s2 * (1.f/DD) - mu*mu;
  float rs = rsqrtf(var + 1e-5f);
  #pragma unroll
  for (int i = 0; i < 3; i++) {
    int c = tid + i*256;
    float o = (v[i] - mu) * rs * g[c] + b[c];
    out[(size_t)row * DD + c] = f2b(o);
  }
}

// causal depthwise conv (K=4) + silu over the xc half of xz
__global__ void conv_silu_kernel(const bf16* __restrict__ xz, const float* __restrict__ cw,
                                 const float* __restrict__ cb, bf16* __restrict__ xc)
{
  int d = blockIdx.x * 256 + threadIdx.x;   // 0..1535
  int row = blockIdx.y;                      // 0..4095
  int b = row >> 11, t = row & 2047;
  float acc = cb[d];
  float w0 = cw[d*4+0], w1 = cw[d*4+1], w2 = cw[d*4+2], w3 = cw[d*4+3];
  const bf16* base = xz + (size_t)(b*2048) * 3072 + d;
  if (t >= 3) acc += b2f(base[(size_t)(t-3)*3072]) * w0;
  if (t >= 2) acc += b2f(base[(size_t)(t-2)*3072]) * w1;
  if (t >= 1) acc += b2f(base[(size_t)(t-1)*3072]) * w2;
  acc += b2f(base[(size_t)t*3072]) * w3;
  float y = acc / (1.f + __expf(-acc));
  xc[(size_t)row * DI + d] = f2b(y);
}

// fp32 -> bf16 conversion
__global__ void cvt_kernel(const float* __restrict__ src, bf16* __restrict__ dst, int n)
{
  int i = blockIdx.x * 256 + threadIdx.x;
  if (i < n) dst[i] = f2b(src[i]);
}

// dt_w (1536,48) fp32 -> (1536,64) bf16 zero-padded
__global__ void prep_dtw_kernel(const float* __restrict__ dtw, bf16* __restrict__ pad)
{
  int i = blockIdx.x * 256 + threadIdx.x;   // 1536*64
  int r = i >> 6, c = i & 63;
  pad[i] = (c < 48) ? f2b(dtw[r*48 + c]) : f2b(0.f);
}

__global__ void prep_A_kernel(const float* __restrict__ alog, float* __restrict__ an)
{
  int i = blockIdx.x * 256 + threadIdx.x;   // 1536*16
  an[i] = -__expf(alog[i]);
}

// SSM scan: 16 lanes per channel (one per state). grid (DI/16, NB)
// yout may alias xc (within a wave, loads of step t issue before the t-store).
__global__ void scan_kernel(const bf16* __restrict__ dt, const bf16* __restrict__ xc,
                            const bf16* __restrict__ dbc, const bf16* __restrict__ xz,
                            const float* __restrict__ An, const float* __restrict__ Dp,
                            bf16* __restrict__ yout)
{
  const int s  = threadIdx.x & 15;
  const int ch = threadIdx.x >> 4;          // 0..15
  const int d  = blockIdx.x * 16 + ch;
  const int b  = blockIdx.y;
  const float A  = An[d*16 + s];
  const float Dd = Dp[d];
  float h = 0.f;
  const int base = b * 2048;
  for (int t = 0; t < 2048; ++t) {
    const int row = base + t;
    float dtv = b2f(dt[(size_t)row * DI + d]);
    float xv  = b2f(xc[(size_t)row * DI + d]);
    float Bv  = b2f(dbc[(size_t)row * 96 + 48 + s]);
    float Cv  = b2f(dbc[(size_t)row * 96 + 64 + s]);
    float dA  = __expf(dtv * A);
    h = dA * h + dtv * xv * Bv;
    float p = h * Cv;
    p += __shfl_xor(p, 1, 16);
    p += __shfl_xor(p, 2, 16);
    p += __shfl_xor(p, 4, 16);
    p += __shfl_xor(p, 8, 16);
    if (s == 0) {
      float zv = b2f(xz[(size_t)row * 3072 + 1536 + d]);
      float yg = (p + xv * Dd) * (zv / (1.f + __expf(-zv)));
      yout[(size_t)row * DI + d] = f2b(yg);
    }
  }
}

static inline void cvt(const float* s, bf16* d, int n, hipStream_t st) {
  cvt_kernel<<<(n + 255)/256, 256, 0, st>>>(s, d, n);
}

extern "C" void kernel_launch(void* const* d_in, const int* in_sizes, int n_in,
                              void* d_out, int out_size, void* d_ws, size_t ws_size,
                              hipStream_t stream)
{
  const float* x      = (const float*)d_in[0];
  const float* norm_g = (const float*)d_in[1];
  const float* norm_b = (const float*)d_in[2];
  const float* mix_w  = (const float*)d_in[21];
  const float* mix_b  = (const float*)d_in[22];
  const float* ffn_w1 = (const float*)d_in[23];
  const float* ffn_b1 = (const float*)d_in[24];
  const float* ffn_w2 = (const float*)d_in[25];
  const float* ffn_b2 = (const float*)d_in[26];
  const float* ffn_ng = (const float*)d_in[27];
  const float* ffn_nb = (const float*)d_in[28];

  // workspace layout (~102 MB)
  size_t o = 0;
  char* wsb = (char*)d_ws;
  auto nxt = [&](size_t bytes) -> char* {
    char* p = wsb + o; o += (bytes + 255) & ~(size_t)255; return p;
  };
  float* An   = (float*)nxt((size_t)DI*DS*4);
  bf16*  dtwp = (bf16*) nxt((size_t)DI*64*2);
  bf16*  w_in = (bf16*) nxt((size_t)2*DI*DD*2);     // per-dir in_proj weight
  bf16*  w_xp = (bf16*) nxt((size_t)80*DI*2);       // per-dir xproj weight
  bf16*  w_out= (bf16*) nxt((size_t)DD*DI*2);       // per-dir out_proj weight
  bf16*  w_mix= (bf16*) nxt((size_t)DD*2*DD*2);
  bf16*  w_f1 = (bf16*) nxt((size_t)4*DD*DD*2);
  bf16*  w_f2 = (bf16*) nxt((size_t)DD*4*DD*2);
  bf16*  dbc  = (bf16*) nxt((size_t)MM*96*2);
  bf16*  xn   = (bf16*) nxt((size_t)MM*DD*2);       // later reused as hn
  bf16*  xc   = (bf16*) nxt((size_t)MM*DI*2);       // ybuf aliases this
  bf16*  dtb  = (bf16*) nxt((size_t)MM*DI*2);
  bf16*  xfb  = (bf16*) nxt((size_t)MM*DI*2);
  float* hbuf = (float*)nxt((size_t)MM*DD*4);
  bf16*  xz   = (bf16*) nxt((size_t)MM*2*DI*2);     // later reused as a1
  bf16*  ybuf = xc;
  bf16*  hn   = xn;
  bf16*  a1   = xz;

  // convert shared weights once
  cvt(mix_w,  w_mix, DD*2*DD, stream);
  cvt(ffn_w1, w_f1, 4*DD*DD, stream);
  cvt(ffn_w2, w_f2, DD*4*DD, stream);

  // 1) LN(x) -> xn (bf16)
  ln_kernel<<<MM, 256, 0, stream>>>(x, norm_g, norm_b, xn);

  for (int dir = 0; dir < 2; ++dir) {
    const float* in_w  = (const float*)d_in[3 + dir*9 + 0];
    const float* convw = (const float*)d_in[3 + dir*9 + 1];
    const float* convb = (const float*)d_in[3 + dir*9 + 2];
    const float* xprjw = (const float*)d_in[3 + dir*9 + 3];
    const float* dt_w  = (const float*)d_in[3 + dir*9 + 4];
    const float* dt_b  = (const float*)d_in[3 + dir*9 + 5];
    const float* alog  = (const float*)d_in[3 + dir*9 + 6];
    const float* Dp    = (const float*)d_in[3 + dir*9 + 7];
    const float* out_w = (const float*)d_in[3 + dir*9 + 8];

    cvt(in_w,  w_in,  2*DI*DD, stream);
    cvt(xprjw, w_xp,  80*DI,   stream);
    cvt(out_w, w_out, DD*DI,   stream);
    prep_dtw_kernel<<<(DI*64)/256, 256, 0, stream>>>(dt_w, dtwp);
    prep_A_kernel<<<(DI*DS)/256, 256, 0, stream>>>(alog, An);

    // in_proj: (4096,768) @ (3072,768)^T -> xz; dir=1 reads xn row-flipped
    gemm_kernel<<<dim3(32, 24), 256, 0, stream>>>(xn, DD, w_in, DD, xz, 2*DI,
                                                  2*DI, DD, nullptr, nullptr, 0,
                                                  ACT_NONE, 0, 0, dir);
    // conv + silu -> xc
    conv_silu_kernel<<<dim3(6, MM), 256, 0, stream>>>(xz, convw, convb, xc);
    // xproj: (4096,1536) @ (80,1536)^T -> dbc (4096, 96-padded)
    gemm_kernel<<<dim3(32, 1), 256, 0, stream>>>(xc, DI, w_xp, DI, dbc, 96,
                                                 80, DI, nullptr, nullptr, 0,
                                                 ACT_NONE, 0, 0, 0);
    // dt: softplus(dbc[:, :64pad] @ dtwp^T + dt_b) -> bf16 (4096,1536)
    gemm_kernel<<<dim3(32, 12), 256, 0, stream>>>(dbc, 96, dtwp, 64, dtb, DI,
                                                  DI, 64, dt_b, nullptr, 0,
                                                  ACT_SOFTPLUS, 0, 0, 0);
    // scan + gating -> ybuf (= xc)
    scan_kernel<<<dim3(DI/16, NB), 256, 0, stream>>>(dtb, xc, dbc, xz, An, Dp, ybuf);
    // out_proj: (4096,1536) @ (768,1536)^T -> xfb half (flip rows for backward)
    gemm_kernel<<<dim3(32, 6), 256, 0, stream>>>(ybuf, DI, w_out, DI,
                                                 xfb + (dir ? DD : 0), 2*DD,
                                                 DD, DI, nullptr, nullptr, 0,
                                                 ACT_NONE, 0, dir, 0);
  }

  // mix: xfb @ mix_w^T + mix_b + x -> hbuf (fp32)
  gemm_kernel<<<dim3(32, 6), 256, 0, stream>>>(xfb, 2*DD, w_mix, 2*DD, hbuf, DD,
                                               DD, 2*DD, mix_b, x, DD,
                                               ACT_NONE, 1, 0, 0);
  // LN2 -> hn (= xn)
  ln_kernel<<<MM, 256, 0, stream>>>(hbuf, ffn_ng, ffn_nb, hn);
  // ffn1: gelu(hn @ w1^T + b1) -> a1 (= xz)
  gemm_kernel<<<dim3(32, 24), 256, 0, stream>>>(hn, DD, w_f1, DD, a1, 4*DD,
                                                4*DD, DD, ffn_b1, nullptr, 0,
                                                ACT_GELU, 0, 0, 0);
  // ffn2: a1 @ w2^T + b2 + hbuf -> d_out (fp32)
  gemm_kernel<<<dim3(32, 6), 256, 0, stream>>>(a1, 4*DD, w_f2, 4*DD, d_out, DD,
                                               DD, 4*DD, ffn_b2, hbuf, DD,
                                               ACT_NONE, 1, 0, 0);
}

// Round 4
// 953.294 us; speedup vs baseline: 3.9743x; 3.9743x over previous
//
#include <hip/hip_runtime.h>
#include <hip/hip_bf16.h>
#include <math.h>

#define NB 2
#define LL 2048
#define DD 768
#define DI 1536
#define DS 16
#define MM (NB*LL)   // 4096
#define TCH 64       // chunk length
#define NCH 32       // 2048 / TCH

typedef __hip_bfloat16 bf16;
typedef __attribute__((ext_vector_type(8))) __bf16 bf16x8;
typedef __attribute__((ext_vector_type(4))) float f32x4;

__device__ __forceinline__ float b2f(bf16 v){ return __bfloat162float(v); }
__device__ __forceinline__ bf16 f2b(float v){ return __float2bfloat16(v); }

__device__ __forceinline__ void un2(unsigned u, float& lo, float& hi){
  union {unsigned i; float f;} a, b;
  a.i = u << 16; b.i = u & 0xffff0000u;
  lo = a.f; hi = b.f;
}

__device__ __forceinline__ void async_cp16(const bf16* g, __bf16* l) {
  __builtin_amdgcn_global_load_lds((const __attribute__((address_space(1))) void*)g,
                                   (__attribute__((address_space(3))) void*)l, 16, 0, 0);
}

#define ACT_NONE 0
#define ACT_SOFTPLUS 1
#define ACT_GELU 2

// C[M,N] = A[M,K] @ B[N,K]^T  (+bias fp32) ->act (+addp fp32)
// flipA: read A row (row^2047)   flipstore: write C row (row^2047)
__global__ void gemm_kernel(const bf16* __restrict__ A, int lda,
                            const bf16* __restrict__ B, int ldb,
                            void* __restrict__ C, int ldc,
                            int N, int K,
                            const float* __restrict__ bias,
                            const float* __restrict__ addp, int ldadd,
                            int act, int f32out, int flipstore, int flipA)
{
  __shared__ __bf16 As[128*32];
  __shared__ __bf16 Bs[128*32];
  const int tid  = threadIdx.x;
  const int lane = tid & 63, wave = tid >> 6;
  const int m0 = blockIdx.x * 128, n0 = blockIdx.y * 128;
  const int wm = wave & 1, wn = wave >> 1;

  const int srow = wave*32 + (lane >> 2);
  const int scol = (lane & 3) * 8;
  int ar0 = m0 + srow, ar1 = m0 + srow + 16;
  if (flipA) { ar0 ^= 2047; ar1 ^= 2047; }
  const bf16* Ag0 = A + (size_t)ar0 * lda + scol;
  const bf16* Ag1 = A + (size_t)ar1 * lda + scol;
  int br0 = n0 + srow;      if (br0 > N-1) br0 = N-1;
  int br1 = n0 + srow + 16; if (br1 > N-1) br1 = N-1;
  const bf16* Bg0 = B + (size_t)br0 * ldb + scol;
  const bf16* Bg1 = B + (size_t)br1 * ldb + scol;
  __bf16* AsW0 = &As[(wave*32     )*32];
  __bf16* AsW1 = &As[(wave*32 + 16)*32];
  __bf16* BsW0 = &Bs[(wave*32     )*32];
  __bf16* BsW1 = &Bs[(wave*32 + 16)*32];

  f32x4 acc[4][4] = {};
  const int arow = wm*64 + (lane & 15);
  const int brow = wn*64 + (lane & 15);
  const int kgrp = (lane >> 4) * 8;

  for (int kb = 0; kb < K; kb += 32) {
    __syncthreads();
    async_cp16(Ag0 + kb, AsW0);
    async_cp16(Ag1 + kb, AsW1);
    async_cp16(Bg0 + kb, BsW0);
    async_cp16(Bg1 + kb, BsW1);
    __syncthreads();
    bf16x8 af[4], bfr[4];
    #pragma unroll
    for (int i = 0; i < 4; i++) af[i]  = *(const bf16x8*)&As[(arow + i*16)*32 + kgrp];
    #pragma unroll
    for (int j = 0; j < 4; j++) bfr[j] = *(const bf16x8*)&Bs[(brow + j*16)*32 + kgrp];
    #pragma unroll
    for (int i = 0; i < 4; i++)
      #pragma unroll
      for (int j = 0; j < 4; j++)
        acc[i][j] = __builtin_amdgcn_mfma_f32_16x16x32_bf16(af[i], bfr[j], acc[i][j], 0, 0, 0);
  }

  bf16*  Cb = (bf16*)C;
  float* Cf = (float*)C;
  #pragma unroll
  for (int i = 0; i < 4; i++) {
    int rbase = m0 + wm*64 + i*16 + (lane >> 4)*4;
    #pragma unroll
    for (int j = 0; j < 4; j++) {
      int col = n0 + wn*64 + j*16 + (lane & 15);
      if (col >= N) continue;
      float bv = bias ? bias[col] : 0.f;
      #pragma unroll
      for (int r = 0; r < 4; r++) {
        int row = rbase + r;
        float v = acc[i][j][r] + bv;
        if (act == ACT_SOFTPLUS) {
          v = (v > 15.f) ? v : log1pf(__expf(v));
        } else if (act == ACT_GELU) {
          float u = 0.7978845608028654f * (v + 0.044715f*v*v*v);
          v = 0.5f * v * (1.f + tanhf(u));
        }
        if (addp) v += addp[(size_t)row * ldadd + col];
        int rs = flipstore ? (row ^ 2047) : row;
        if (f32out) Cf[(size_t)rs * ldc + col] = v;
        else        Cb[(size_t)rs * ldc + col] = f2b(v);
      }
    }
  }
}

// LayerNorm over D=768; fp32 in, bf16 out
__global__ void ln_kernel(const float* __restrict__ x, const float* __restrict__ g,
                          const float* __restrict__ b, bf16* __restrict__ out)
{
  const int row = blockIdx.x;
  const int tid = threadIdx.x;
  const float* xr = x + (size_t)row * DD;
  float v[3], s = 0.f, s2 = 0.f;
  #pragma unroll
  for (int i = 0; i < 3; i++) {
    float f = xr[tid + i*256];
    v[i] = f; s += f; s2 += f*f;
  }
  #pragma unroll
  for (int o = 32; o > 0; o >>= 1) { s += __shfl_down(s, o, 64); s2 += __shfl_down(s2, o, 64); }
  __shared__ float ps[4], ps2[4];
  int wave = tid >> 6;
  if ((tid & 63) == 0) { ps[wave] = s; ps2[wave] = s2; }
  __syncthreads();
  s = ps[0]+ps[1]+ps[2]+ps[3]; s2 = ps2[0]+ps2[1]+ps2[2]+ps2[3];
  float mu = s * (1.f/DD);
  float var = s2 * (1.f/DD) - mu*mu;
  float rs = rsqrtf(var + 1e-5f);
  #pragma unroll
  for (int i = 0; i < 3; i++) {
    int c = tid + i*256;
    float o = (v[i] - mu) * rs * g[c] + b[c];
    out[(size_t)row * DD + c] = f2b(o);
  }
}

// causal depthwise conv (K=4) + silu over the xc half of xz
__global__ void conv_silu_kernel(const bf16* __restrict__ xz, const float* __restrict__ cw,
                                 const float* __restrict__ cb, bf16* __restrict__ xc)
{
  int d = blockIdx.x * 256 + threadIdx.x;
  int row = blockIdx.y;
  int b = row >> 11, t = row & 2047;
  float acc = cb[d];
  float w0 = cw[d*4+0], w1 = cw[d*4+1], w2 = cw[d*4+2], w3 = cw[d*4+3];
  const bf16* base = xz + (size_t)(b*2048) * 3072 + d;
  if (t >= 3) acc += b2f(base[(size_t)(t-3)*3072]) * w0;
  if (t >= 2) acc += b2f(base[(size_t)(t-2)*3072]) * w1;
  if (t >= 1) acc += b2f(base[(size_t)(t-1)*3072]) * w2;
  acc += b2f(base[(size_t)t*3072]) * w3;
  float y = acc / (1.f + __expf(-acc));
  xc[(size_t)row * DI + d] = f2b(y);
}

__global__ void cvt_kernel(const float* __restrict__ src, bf16* __restrict__ dst, int n)
{
  int i = blockIdx.x * 256 + threadIdx.x;
  if (i < n) dst[i] = f2b(src[i]);
}

__global__ void prep_dtw_kernel(const float* __restrict__ dtw, bf16* __restrict__ pad)
{
  int i = blockIdx.x * 256 + threadIdx.x;   // 1536*64
  int r = i >> 6, c = i & 63;
  pad[i] = (c < 48) ? f2b(dtw[r*48 + c]) : f2b(0.f);
}

// An transposed to [s][DI] for coalesced per-d access
__global__ void prep_A_kernel(const float* __restrict__ alog, float* __restrict__ an)
{
  int i = blockIdx.x * 256 + threadIdx.x;   // DI*16
  int d = i >> 4, s = i & 15;
  an[s*DI + d] = -__expf(alog[i]);
}

// ---- chunked parallel scan ----
// Pass A: per (d-block, chunk, b): P = prod dA, S = local scan from h=0.
// layout of P/S/h0: [(b*NCH+c)*DI + d]*16 + s
__global__ void scan_partial(const bf16* __restrict__ dt, const bf16* __restrict__ xc,
                             const bf16* __restrict__ dbc, const float* __restrict__ An,
                             float* __restrict__ Pp, float* __restrict__ Sp)
{
  const int tid = threadIdx.x;
  const int d = blockIdx.x * 256 + tid;
  const int c = blockIdx.y, b = blockIdx.z;
  const int rowbase = b*2048 + c*TCH;
  __shared__ unsigned bcs[TCH*16];   // 32 bf16 (B then C) per row
  for (int i = tid; i < TCH*16; i += 256) {
    int r = i >> 4, dw = i & 15;
    bcs[i] = ((const unsigned*)(dbc + (size_t)(rowbase + r)*96 + 48))[dw];
  }
  __syncthreads();
  float A[16], P[16], g[16];
  #pragma unroll
  for (int s = 0; s < 16; s++) { A[s] = An[s*DI + d]; P[s] = 1.f; g[s] = 0.f; }
  float dtv = b2f(dt[(size_t)rowbase*DI + d]);
  float xv  = b2f(xc[(size_t)rowbase*DI + d]);
  for (int t = 0; t < TCH; t++) {
    float dtn = 0.f, xvn = 0.f;
    if (t + 1 < TCH) {
      dtn = b2f(dt[(size_t)(rowbase+t+1)*DI + d]);
      xvn = b2f(xc[(size_t)(rowbase+t+1)*DI + d]);
    }
    unsigned ub[8];
    *(uint4*)&ub[0] = *(const uint4*)&bcs[t*16];
    *(uint4*)&ub[4] = *(const uint4*)&bcs[t*16 + 4];
    float Bv[16];
    #pragma unroll
    for (int k = 0; k < 8; k++) un2(ub[k], Bv[2*k], Bv[2*k+1]);
    float u = dtv * xv;
    #pragma unroll
    for (int s = 0; s < 16; s++) {
      float dA = __expf(dtv * A[s]);
      P[s] *= dA;
      g[s] = dA * g[s] + u * Bv[s];
    }
    dtv = dtn; xv = xvn;
  }
  size_t base = ((size_t)(b*NCH + c)*DI + d) * 16;
  #pragma unroll
  for (int s = 0; s < 16; s++) { Pp[base+s] = P[s]; Sp[base+s] = g[s]; }
}

// Pass B: inter-chunk scan. grid(96, NB), 256 thr. j = d*16+s
__global__ void scan_combine(const float* __restrict__ Pp, const float* __restrict__ Sp,
                             float* __restrict__ h0)
{
  const int j = blockIdx.x * 256 + threadIdx.x;   // 0..DI*16-1
  const int b = blockIdx.y;
  float h = 0.f;
  for (int c = 0; c < NCH; c++) {
    size_t idx = ((size_t)(b*NCH + c)*DI)*16 + j;
    h0[idx] = h;
    h = Pp[idx]*h + Sp[idx];
  }
}

// Pass C: re-run chunk from h0, emit gated y. yout may alias xc.
__global__ void scan_final(const bf16* __restrict__ dt, const bf16* __restrict__ xc,
                           const bf16* __restrict__ dbc, const bf16* __restrict__ xz,
                           const float* __restrict__ An, const float* __restrict__ Dp,
                           const float* __restrict__ h0, bf16* __restrict__ yout)
{
  const int tid = threadIdx.x;
  const int d = blockIdx.x * 256 + tid;
  const int c = blockIdx.y, b = blockIdx.z;
  const int rowbase = b*2048 + c*TCH;
  __shared__ unsigned bcs[TCH*16];
  for (int i = tid; i < TCH*16; i += 256) {
    int r = i >> 4, dw = i & 15;
    bcs[i] = ((const unsigned*)(dbc + (size_t)(rowbase + r)*96 + 48))[dw];
  }
  __syncthreads();
  float A[16], h[16];
  size_t hbase = ((size_t)(b*NCH + c)*DI + d) * 16;
  #pragma unroll
  for (int s = 0; s < 16; s++) { A[s] = An[s*DI + d]; h[s] = h0[hbase+s]; }
  const float Dd = Dp[d];
  float dtv = b2f(dt[(size_t)rowbase*DI + d]);
  float xv  = b2f(xc[(size_t)rowbase*DI + d]);
  for (int t = 0; t < TCH; t++) {
    const int row = rowbase + t;
    float dtn = 0.f, xvn = 0.f;
    if (t + 1 < TCH) {
      dtn = b2f(dt[(size_t)(row+1)*DI + d]);
      xvn = b2f(xc[(size_t)(row+1)*DI + d]);
    }
    unsigned ub[8], uc[8];
    *(uint4*)&ub[0] = *(const uint4*)&bcs[t*16];
    *(uint4*)&ub[4] = *(const uint4*)&bcs[t*16 + 4];
    *(uint4*)&uc[0] = *(const uint4*)&bcs[t*16 + 8];
    *(uint4*)&uc[4] = *(const uint4*)&bcs[t*16 + 12];
    float Bv[16], Cv[16];
    #pragma unroll
    for (int k = 0; k < 8; k++) { un2(ub[k], Bv[2*k], Bv[2*k+1]); un2(uc[k], Cv[2*k], Cv[2*k+1]); }
    float u = dtv * xv;
    float y = 0.f;
    #pragma unroll
    for (int s = 0; s < 16; s++) {
      float dA = __expf(dtv * A[s]);
      h[s] = dA * h[s] + u * Bv[s];
      y += h[s] * Cv[s];
    }
    float zv = b2f(xz[(size_t)row*3072 + 1536 + d]);
    float yg = (y + xv * Dd) * (zv / (1.f + __expf(-zv)));
    yout[(size_t)row*DI + d] = f2b(yg);
    dtv = dtn; xv = xvn;
  }
}

static inline void cvt(const float* s, bf16* d, int n, hipStream_t st) {
  cvt_kernel<<<(n + 255)/256, 256, 0, st>>>(s, d, n);
}

extern "C" void kernel_launch(void* const* d_in, const int* in_sizes, int n_in,
                              void* d_out, int out_size, void* d_ws, size_t ws_size,
                              hipStream_t stream)
{
  const float* x      = (const float*)d_in[0];
  const float* norm_g = (const float*)d_in[1];
  const float* norm_b = (const float*)d_in[2];
  const float* mix_w  = (const float*)d_in[21];
  const float* mix_b  = (const float*)d_in[22];
  const float* ffn_w1 = (const float*)d_in[23];
  const float* ffn_b1 = (const float*)d_in[24];
  const float* ffn_w2 = (const float*)d_in[25];
  const float* ffn_b2 = (const float*)d_in[26];
  const float* ffn_ng = (const float*)d_in[27];
  const float* ffn_nb = (const float*)d_in[28];

  // workspace (~108 MB); hbuf aliases scan scratch (disjoint lifetimes)
  size_t o = 0;
  char* wsb = (char*)d_ws;
  auto nxt = [&](size_t bytes) -> char* {
    char* p = wsb + o; o += (bytes + 255) & ~(size_t)255; return p;
  };
  float* An   = (float*)nxt((size_t)DI*DS*4);
  bf16*  dtwp = (bf16*) nxt((size_t)DI*64*2);
  bf16*  w_in = (bf16*) nxt((size_t)2*DI*DD*2);
  bf16*  w_xp = (bf16*) nxt((size_t)80*DI*2);
  bf16*  w_out= (bf16*) nxt((size_t)DD*DI*2);
  bf16*  w_mix= (bf16*) nxt((size_t)DD*2*DD*2);
  bf16*  w_f1 = (bf16*) nxt((size_t)4*DD*DD*2);
  bf16*  w_f2 = (bf16*) nxt((size_t)DD*4*DD*2);
  bf16*  dbc  = (bf16*) nxt((size_t)MM*96*2);
  bf16*  xn   = (bf16*) nxt((size_t)MM*DD*2);       // reused as hn
  bf16*  xc   = (bf16*) nxt((size_t)MM*DI*2);       // ybuf aliases this
  bf16*  dtb  = (bf16*) nxt((size_t)MM*DI*2);
  bf16*  xfb  = (bf16*) nxt((size_t)MM*DI*2);
  float* Pp   = (float*)nxt((size_t)NB*NCH*DI*16*4);  // 6.3MB
  float* Sp   = (float*)nxt((size_t)NB*NCH*DI*16*4);
  float* h0   = (float*)nxt((size_t)NB*NCH*DI*16*4);
  bf16*  xz   = (bf16*) nxt((size_t)MM*2*DI*2);     // reused as a1
  bf16*  ybuf = xc;
  bf16*  hn   = xn;
  bf16*  a1   = xz;
  float* hbuf = Pp;   // 12.6MB needed, 18.9MB available; dead scan scratch by then

  cvt(mix_w,  w_mix, DD*2*DD, stream);
  cvt(ffn_w1, w_f1, 4*DD*DD, stream);
  cvt(ffn_w2, w_f2, DD*4*DD, stream);

  ln_kernel<<<MM, 256, 0, stream>>>(x, norm_g, norm_b, xn);

  for (int dir = 0; dir < 2; ++dir) {
    const float* in_w  = (const float*)d_in[3 + dir*9 + 0];
    const float* convw = (const float*)d_in[3 + dir*9 + 1];
    const float* convb = (const float*)d_in[3 + dir*9 + 2];
    const float* xprjw = (const float*)d_in[3 + dir*9 + 3];
    const float* dt_w  = (const float*)d_in[3 + dir*9 + 4];
    const float* dt_b  = (const float*)d_in[3 + dir*9 + 5];
    const float* alog  = (const float*)d_in[3 + dir*9 + 6];
    const float* Dp    = (const float*)d_in[3 + dir*9 + 7];
    const float* out_w = (const float*)d_in[3 + dir*9 + 8];

    cvt(in_w,  w_in,  2*DI*DD, stream);
    cvt(xprjw, w_xp,  80*DI,   stream);
    cvt(out_w, w_out, DD*DI,   stream);
    prep_dtw_kernel<<<(DI*64)/256, 256, 0, stream>>>(dt_w, dtwp);
    prep_A_kernel<<<(DI*DS)/256, 256, 0, stream>>>(alog, An);

    gemm_kernel<<<dim3(32, 24), 256, 0, stream>>>(xn, DD, w_in, DD, xz, 2*DI,
                                                  2*DI, DD, nullptr, nullptr, 0,
                                                  ACT_NONE, 0, 0, dir);
    conv_silu_kernel<<<dim3(6, MM), 256, 0, stream>>>(xz, convw, convb, xc);
    gemm_kernel<<<dim3(32, 1), 256, 0, stream>>>(xc, DI, w_xp, DI, dbc, 96,
                                                 80, DI, nullptr, nullptr, 0,
                                                 ACT_NONE, 0, 0, 0);
    gemm_kernel<<<dim3(32, 12), 256, 0, stream>>>(dbc, 96, dtwp, 64, dtb, DI,
                                                  DI, 64, dt_b, nullptr, 0,
                                                  ACT_SOFTPLUS, 0, 0, 0);
    // chunked parallel scan
    scan_partial<<<dim3(DI/256, NCH, NB), 256, 0, stream>>>(dtb, xc, dbc, An, Pp, Sp);
    scan_combine<<<dim3(DI*16/256, NB), 256, 0, stream>>>(Pp, Sp, h0);
    scan_final<<<dim3(DI/256, NCH, NB), 256, 0, stream>>>(dtb, xc, dbc, xz, An, Dp, h0, ybuf);

    gemm_kernel<<<dim3(32, 6), 256, 0, stream>>>(ybuf, DI, w_out, DI,
                                                 xfb + (dir ? DD : 0), 2*DD,
                                                 DD, DI, nullptr, nullptr, 0,
                                                 ACT_NONE, 0, dir, 0);
  }

  gemm_kernel<<<dim3(32, 6), 256, 0, stream>>>(xfb, 2*DD, w_mix, 2*DD, hbuf, DD,
                                               DD, 2*DD, mix_b, x, DD,
                                               ACT_NONE, 1, 0, 0);
  ln_kernel<<<MM, 256, 0, stream>>>(hbuf, ffn_ng, ffn_nb, hn);
  gemm_kernel<<<dim3(32, 24), 256, 0, stream>>>(hn, DD, w_f1, DD, a1, 4*DD,
                                                4*DD, DD, ffn_b1, nullptr, 0,
                                                ACT_GELU, 0, 0, 0);
  gemm_kernel<<<dim3(32, 6), 256, 0, stream>>>(a1, 4*DD, w_f2, 4*DD, d_out, DD,
                                               DD, 4*DD, ffn_b2, hbuf, DD,
                                               ACT_NONE, 1, 0, 0);
}

// Round 5
// 784.245 us; speedup vs baseline: 4.8310x; 1.2156x over previous
//
#include <hip/hip_runtime.h>
#include <hip/hip_bf16.h>
#include <math.h>

#define NB 2
#define LL 2048
#define DD 768
#define DI 1536
#define DS 16
#define MM (NB*LL)   // 4096
#define TCH 64       // chunk length
#define NCH 32       // 2048 / TCH

typedef __hip_bfloat16 bf16;
typedef __attribute__((ext_vector_type(8))) __bf16 bf16x8;
typedef __attribute__((ext_vector_type(4))) float f32x4;

__device__ __forceinline__ float b2f(bf16 v){ return __bfloat162float(v); }
__device__ __forceinline__ bf16 f2b(float v){ return __float2bfloat16(v); }

__device__ __forceinline__ void un2(unsigned u, float& lo, float& hi){
  union {unsigned i; float f;} a, b;
  a.i = u << 16; b.i = u & 0xffff0000u;
  lo = a.f; hi = b.f;
}

__device__ __forceinline__ void async_cp16(const bf16* g, __bf16* l) {
  __builtin_amdgcn_global_load_lds((const __attribute__((address_space(1))) void*)g,
                                   (__attribute__((address_space(3))) void*)l, 16, 0, 0);
}

#define ACT_NONE 0
#define ACT_SOFTPLUS 1
#define ACT_GELU 2

__device__ __forceinline__ float apply_act(float v, int act) {
  if (act == ACT_SOFTPLUS) {
    v = (v > 15.f) ? v : log1pf(__expf(v));
  } else if (act == ACT_GELU) {
    float u = 0.7978845608028654f * (v + 0.044715f*v*v*v);
    v = 0.5f * v * (1.f + tanhf(u));
  }
  return v;
}

// 128x128 tile GEMM: C[M,N] = A[M,K] @ B[N,K]^T (+bias) ->act (+addp)
__global__ void gemm_kernel(const bf16* __restrict__ A, int lda,
                            const bf16* __restrict__ B, int ldb,
                            void* __restrict__ C, int ldc,
                            int N, int K,
                            const float* __restrict__ bias,
                            const float* __restrict__ addp, int ldadd,
                            int act, int f32out, int flipstore, int flipA)
{
  __shared__ __bf16 As[128*32];
  __shared__ __bf16 Bs[128*32];
  const int tid  = threadIdx.x;
  const int lane = tid & 63, wave = tid >> 6;
  const int m0 = blockIdx.x * 128, n0 = blockIdx.y * 128;
  const int wm = wave & 1, wn = wave >> 1;

  const int srow = wave*32 + (lane >> 2);
  const int scol = (lane & 3) * 8;
  int ar0 = m0 + srow, ar1 = m0 + srow + 16;
  if (flipA) { ar0 ^= 2047; ar1 ^= 2047; }
  const bf16* Ag0 = A + (size_t)ar0 * lda + scol;
  const bf16* Ag1 = A + (size_t)ar1 * lda + scol;
  int br0 = n0 + srow;      if (br0 > N-1) br0 = N-1;
  int br1 = n0 + srow + 16; if (br1 > N-1) br1 = N-1;
  const bf16* Bg0 = B + (size_t)br0 * ldb + scol;
  const bf16* Bg1 = B + (size_t)br1 * ldb + scol;
  __bf16* AsW0 = &As[(wave*32     )*32];
  __bf16* AsW1 = &As[(wave*32 + 16)*32];
  __bf16* BsW0 = &Bs[(wave*32     )*32];
  __bf16* BsW1 = &Bs[(wave*32 + 16)*32];

  f32x4 acc[4][4] = {};
  const int arow = wm*64 + (lane & 15);
  const int brow = wn*64 + (lane & 15);
  const int kgrp = (lane >> 4) * 8;

  for (int kb = 0; kb < K; kb += 32) {
    __syncthreads();
    async_cp16(Ag0 + kb, AsW0);
    async_cp16(Ag1 + kb, AsW1);
    async_cp16(Bg0 + kb, BsW0);
    async_cp16(Bg1 + kb, BsW1);
    __syncthreads();
    bf16x8 af[4], bfr[4];
    #pragma unroll
    for (int i = 0; i < 4; i++) af[i]  = *(const bf16x8*)&As[(arow + i*16)*32 + kgrp];
    #pragma unroll
    for (int j = 0; j < 4; j++) bfr[j] = *(const bf16x8*)&Bs[(brow + j*16)*32 + kgrp];
    #pragma unroll
    for (int i = 0; i < 4; i++)
      #pragma unroll
      for (int j = 0; j < 4; j++)
        acc[i][j] = __builtin_amdgcn_mfma_f32_16x16x32_bf16(af[i], bfr[j], acc[i][j], 0, 0, 0);
  }

  bf16*  Cb = (bf16*)C;
  float* Cf = (float*)C;
  #pragma unroll
  for (int i = 0; i < 4; i++) {
    int rbase = m0 + wm*64 + i*16 + (lane >> 4)*4;
    #pragma unroll
    for (int j = 0; j < 4; j++) {
      int col = n0 + wn*64 + j*16 + (lane & 15);
      if (col >= N) continue;
      float bv = bias ? bias[col] : 0.f;
      #pragma unroll
      for (int r = 0; r < 4; r++) {
        int row = rbase + r;
        float v = apply_act(acc[i][j][r] + bv, act);
        if (addp) v += addp[(size_t)row * ldadd + col];
        int rs = flipstore ? (row ^ 2047) : row;
        if (f32out) Cf[(size_t)rs * ldc + col] = v;
        else        Cb[(size_t)rs * ldc + col] = f2b(v);
      }
    }
  }
}

// 64x64 tile GEMM for skinny-N matmuls (4x block count vs 128-tile)
__global__ void gemm64_kernel(const bf16* __restrict__ A, int lda,
                              const bf16* __restrict__ B, int ldb,
                              void* __restrict__ C, int ldc,
                              int N, int K,
                              const float* __restrict__ bias,
                              const float* __restrict__ addp, int ldadd,
                              int act, int f32out, int flipstore, int flipA)
{
  __shared__ __bf16 As[64*32];
  __shared__ __bf16 Bs[64*32];
  const int tid  = threadIdx.x;
  const int lane = tid & 63, wave = tid >> 6;
  const int m0 = blockIdx.x * 64, n0 = blockIdx.y * 64;
  const int wm = wave & 1, wn = wave >> 1;

  const int srow = wave*16 + (lane >> 2);
  const int scol = (lane & 3) * 8;
  int ar = m0 + srow;
  if (flipA) ar ^= 2047;
  const bf16* Ag = A + (size_t)ar * lda + scol;
  int br = n0 + srow; if (br > N-1) br = N-1;
  const bf16* Bg = B + (size_t)br * ldb + scol;
  __bf16* AsW = &As[(wave*16)*32];
  __bf16* BsW = &Bs[(wave*16)*32];

  f32x4 acc[2][2] = {};
  const int arow = wm*32 + (lane & 15);
  const int brow = wn*32 + (lane & 15);
  const int kgrp = (lane >> 4) * 8;

  for (int kb = 0; kb < K; kb += 32) {
    __syncthreads();
    async_cp16(Ag + kb, AsW);
    async_cp16(Bg + kb, BsW);
    __syncthreads();
    bf16x8 af[2], bfr[2];
    #pragma unroll
    for (int i = 0; i < 2; i++) af[i]  = *(const bf16x8*)&As[(arow + i*16)*32 + kgrp];
    #pragma unroll
    for (int j = 0; j < 2; j++) bfr[j] = *(const bf16x8*)&Bs[(brow + j*16)*32 + kgrp];
    #pragma unroll
    for (int i = 0; i < 2; i++)
      #pragma unroll
      for (int j = 0; j < 2; j++)
        acc[i][j] = __builtin_amdgcn_mfma_f32_16x16x32_bf16(af[i], bfr[j], acc[i][j], 0, 0, 0);
  }

  bf16*  Cb = (bf16*)C;
  float* Cf = (float*)C;
  #pragma unroll
  for (int i = 0; i < 2; i++) {
    int rbase = m0 + wm*32 + i*16 + (lane >> 4)*4;
    #pragma unroll
    for (int j = 0; j < 2; j++) {
      int col = n0 + wn*32 + j*16 + (lane & 15);
      if (col >= N) continue;
      float bv = bias ? bias[col] : 0.f;
      #pragma unroll
      for (int r = 0; r < 4; r++) {
        int row = rbase + r;
        float v = apply_act(acc[i][j][r] + bv, act);
        if (addp) v += addp[(size_t)row * ldadd + col];
        int rs = flipstore ? (row ^ 2047) : row;
        if (f32out) Cf[(size_t)rs * ldc + col] = v;
        else        Cb[(size_t)rs * ldc + col] = f2b(v);
      }
    }
  }
}

// LayerNorm over D=768; fp32 in, bf16 out
__global__ void ln_kernel(const float* __restrict__ x, const float* __restrict__ g,
                          const float* __restrict__ b, bf16* __restrict__ out)
{
  const int row = blockIdx.x;
  const int tid = threadIdx.x;
  const float* xr = x + (size_t)row * DD;
  float v[3], s = 0.f, s2 = 0.f;
  #pragma unroll
  for (int i = 0; i < 3; i++) {
    float f = xr[tid + i*256];
    v[i] = f; s += f; s2 += f*f;
  }
  #pragma unroll
  for (int o = 32; o > 0; o >>= 1) { s += __shfl_down(s, o, 64); s2 += __shfl_down(s2, o, 64); }
  __shared__ float ps[4], ps2[4];
  int wave = tid >> 6;
  if ((tid & 63) == 0) { ps[wave] = s; ps2[wave] = s2; }
  __syncthreads();
  s = ps[0]+ps[1]+ps[2]+ps[3]; s2 = ps2[0]+ps2[1]+ps2[2]+ps2[3];
  float mu = s * (1.f/DD);
  float var = s2 * (1.f/DD) - mu*mu;
  float rs = rsqrtf(var + 1e-5f);
  #pragma unroll
  for (int i = 0; i < 3; i++) {
    int c = tid + i*256;
    float o = (v[i] - mu) * rs * g[c] + b[c];
    out[(size_t)row * DD + c] = f2b(o);
  }
}

// causal depthwise conv (K=4) + silu over the xc half of xz
__global__ void conv_silu_kernel(const bf16* __restrict__ xz, const float* __restrict__ cw,
                                 const float* __restrict__ cb, bf16* __restrict__ xc)
{
  int d = blockIdx.x * 256 + threadIdx.x;
  int row = blockIdx.y;
  int b = row >> 11, t = row & 2047;
  float acc = cb[d];
  float w0 = cw[d*4+0], w1 = cw[d*4+1], w2 = cw[d*4+2], w3 = cw[d*4+3];
  const bf16* base = xz + (size_t)(b*2048) * 3072 + d;
  if (t >= 3) acc += b2f(base[(size_t)(t-3)*3072]) * w0;
  if (t >= 2) acc += b2f(base[(size_t)(t-2)*3072]) * w1;
  if (t >= 1) acc += b2f(base[(size_t)(t-1)*3072]) * w2;
  acc += b2f(base[(size_t)t*3072]) * w3;
  float y = acc / (1.f + __expf(-acc));
  xc[(size_t)row * DI + d] = f2b(y);
}

__global__ void cvt_kernel(const float* __restrict__ src, bf16* __restrict__ dst, int n)
{
  int i = blockIdx.x * 256 + threadIdx.x;
  if (i < n) dst[i] = f2b(src[i]);
}

__global__ void prep_dtw_kernel(const float* __restrict__ dtw, bf16* __restrict__ pad)
{
  int i = blockIdx.x * 256 + threadIdx.x;   // 1536*64
  int r = i >> 6, c = i & 63;
  pad[i] = (c < 48) ? f2b(dtw[r*48 + c]) : f2b(0.f);
}

// An transposed to [s][DI] for coalesced per-d access
__global__ void prep_A_kernel(const float* __restrict__ alog, float* __restrict__ an)
{
  int i = blockIdx.x * 256 + threadIdx.x;   // DI*16
  int d = i >> 4, s = i & 15;
  an[s*DI + d] = -__expf(alog[i]);
}

// ---- chunked parallel scan ----
__global__ void scan_partial(const bf16* __restrict__ dt, const bf16* __restrict__ xc,
                             const bf16* __restrict__ dbc, const float* __restrict__ An,
                             float* __restrict__ Pp, float* __restrict__ Sp)
{
  const int tid = threadIdx.x;
  const int d = blockIdx.x * 256 + tid;
  const int c = blockIdx.y, b = blockIdx.z;
  const int rowbase = b*2048 + c*TCH;
  __shared__ unsigned bcs[TCH*16];
  for (int i = tid; i < TCH*16; i += 256) {
    int r = i >> 4, dw = i & 15;
    bcs[i] = ((const unsigned*)(dbc + (size_t)(rowbase + r)*96 + 48))[dw];
  }
  __syncthreads();
  float A[16], P[16], g[16];
  #pragma unroll
  for (int s = 0; s < 16; s++) { A[s] = An[s*DI + d]; P[s] = 1.f; g[s] = 0.f; }
  float dtv = b2f(dt[(size_t)rowbase*DI + d]);
  float xv  = b2f(xc[(size_t)rowbase*DI + d]);
  for (int t = 0; t < TCH; t++) {
    float dtn = 0.f, xvn = 0.f;
    if (t + 1 < TCH) {
      dtn = b2f(dt[(size_t)(rowbase+t+1)*DI + d]);
      xvn = b2f(xc[(size_t)(rowbase+t+1)*DI + d]);
    }
    unsigned ub[8];
    *(uint4*)&ub[0] = *(const uint4*)&bcs[t*16];
    *(uint4*)&ub[4] = *(const uint4*)&bcs[t*16 + 4];
    float Bv[16];
    #pragma unroll
    for (int k = 0; k < 8; k++) un2(ub[k], Bv[2*k], Bv[2*k+1]);
    float u = dtv * xv;
    #pragma unroll
    for (int s = 0; s < 16; s++) {
      float dA = __expf(dtv * A[s]);
      P[s] *= dA;
      g[s] = dA * g[s] + u * Bv[s];
    }
    dtv = dtn; xv = xvn;
  }
  size_t base = ((size_t)(b*NCH + c)*DI + d) * 16;
  #pragma unroll
  for (int s = 0; s < 16; s++) { Pp[base+s] = P[s]; Sp[base+s] = g[s]; }
}

__global__ void scan_combine(const float* __restrict__ Pp, const float* __restrict__ Sp,
                             float* __restrict__ h0)
{
  const int j = blockIdx.x * 256 + threadIdx.x;
  const int b = blockIdx.y;
  float h = 0.f;
  for (int c = 0; c < NCH; c++) {
    size_t idx = ((size_t)(b*NCH + c)*DI)*16 + j;
    h0[idx] = h;
    h = Pp[idx]*h + Sp[idx];
  }
}

__global__ void scan_final(const bf16* __restrict__ dt, const bf16* __restrict__ xc,
                           const bf16* __restrict__ dbc, const bf16* __restrict__ xz,
                           const float* __restrict__ An, const float* __restrict__ Dp,
                           const float* __restrict__ h0, bf16* __restrict__ yout)
{
  const int tid = threadIdx.x;
  const int d = blockIdx.x * 256 + tid;
  const int c = blockIdx.y, b = blockIdx.z;
  const int rowbase = b*2048 + c*TCH;
  __shared__ unsigned bcs[TCH*16];
  for (int i = tid; i < TCH*16; i += 256) {
    int r = i >> 4, dw = i & 15;
    bcs[i] = ((const unsigned*)(dbc + (size_t)(rowbase + r)*96 + 48))[dw];
  }
  __syncthreads();
  float A[16], h[16];
  size_t hbase = ((size_t)(b*NCH + c)*DI + d) * 16;
  #pragma unroll
  for (int s = 0; s < 16; s++) { A[s] = An[s*DI + d]; h[s] = h0[hbase+s]; }
  const float Dd = Dp[d];
  float dtv = b2f(dt[(size_t)rowbase*DI + d]);
  float xv  = b2f(xc[(size_t)rowbase*DI + d]);
  for (int t = 0; t < TCH; t++) {
    const int row = rowbase + t;
    float dtn = 0.f, xvn = 0.f;
    if (t + 1 < TCH) {
      dtn = b2f(dt[(size_t)(row+1)*DI + d]);
      xvn = b2f(xc[(size_t)(row+1)*DI + d]);
    }
    unsigned ub[8], uc[8];
    *(uint4*)&ub[0] = *(const uint4*)&bcs[t*16];
    *(uint4*)&ub[4] = *(const uint4*)&bcs[t*16 + 4];
    *(uint4*)&uc[0] = *(const uint4*)&bcs[t*16 + 8];
    *(uint4*)&uc[4] = *(const uint4*)&bcs[t*16 + 12];
    float Bv[16], Cv[16];
    #pragma unroll
    for (int k = 0; k < 8; k++) { un2(ub[k], Bv[2*k], Bv[2*k+1]); un2(uc[k], Cv[2*k], Cv[2*k+1]); }
    float u = dtv * xv;
    float y = 0.f;
    #pragma unroll
    for (int s = 0; s < 16; s++) {
      float dA = __expf(dtv * A[s]);
      h[s] = dA * h[s] + u * Bv[s];
      y += h[s] * Cv[s];
    }
    float zv = b2f(xz[(size_t)row*3072 + 1536 + d]);
    float yg = (y + xv * Dd) * (zv / (1.f + __expf(-zv)));
    yout[(size_t)row*DI + d] = f2b(yg);
    dtv = dtn; xv = xvn;
  }
}

static inline void cvt(const float* s, bf16* d, int n, hipStream_t st) {
  cvt_kernel<<<(n + 255)/256, 256, 0, st>>>(s, d, n);
}

extern "C" void kernel_launch(void* const* d_in, const int* in_sizes, int n_in,
                              void* d_out, int out_size, void* d_ws, size_t ws_size,
                              hipStream_t stream)
{
  const float* x      = (const float*)d_in[0];
  const float* norm_g = (const float*)d_in[1];
  const float* norm_b = (const float*)d_in[2];
  const float* mix_w  = (const float*)d_in[21];
  const float* mix_b  = (const float*)d_in[22];
  const float* ffn_w1 = (const float*)d_in[23];
  const float* ffn_b1 = (const float*)d_in[24];
  const float* ffn_w2 = (const float*)d_in[25];
  const float* ffn_b2 = (const float*)d_in[26];
  const float* ffn_ng = (const float*)d_in[27];
  const float* ffn_nb = (const float*)d_in[28];

  size_t o = 0;
  char* wsb = (char*)d_ws;
  auto nxt = [&](size_t bytes) -> char* {
    char* p = wsb + o; o += (bytes + 255) & ~(size_t)255; return p;
  };
  float* An   = (float*)nxt((size_t)DI*DS*4);
  bf16*  dtwp = (bf16*) nxt((size_t)DI*64*2);
  bf16*  w_in = (bf16*) nxt((size_t)2*DI*DD*2);
  bf16*  w_xp = (bf16*) nxt((size_t)80*DI*2);
  bf16*  w_out= (bf16*) nxt((size_t)DD*DI*2);
  bf16*  w_mix= (bf16*) nxt((size_t)DD*2*DD*2);
  bf16*  w_f1 = (bf16*) nxt((size_t)4*DD*DD*2);
  bf16*  w_f2 = (bf16*) nxt((size_t)DD*4*DD*2);
  bf16*  dbc  = (bf16*) nxt((size_t)MM*96*2);
  bf16*  xn   = (bf16*) nxt((size_t)MM*DD*2);       // reused as hn
  bf16*  xc   = (bf16*) nxt((size_t)MM*DI*2);       // ybuf aliases this
  bf16*  dtb  = (bf16*) nxt((size_t)MM*DI*2);
  bf16*  xfb  = (bf16*) nxt((size_t)MM*DI*2);
  float* Pp   = (float*)nxt((size_t)NB*NCH*DI*16*4);
  float* Sp   = (float*)nxt((size_t)NB*NCH*DI*16*4);
  float* h0   = (float*)nxt((size_t)NB*NCH*DI*16*4);
  bf16*  xz   = (bf16*) nxt((size_t)MM*2*DI*2);     // reused as a1
  bf16*  ybuf = xc;
  bf16*  hn   = xn;
  bf16*  a1   = xz;
  float* hbuf = Pp;   // dead scan scratch by the time mix runs

  cvt(mix_w,  w_mix, DD*2*DD, stream);
  cvt(ffn_w1, w_f1, 4*DD*DD, stream);
  cvt(ffn_w2, w_f2, DD*4*DD, stream);

  ln_kernel<<<MM, 256, 0, stream>>>(x, norm_g, norm_b, xn);

  for (int dir = 0; dir < 2; ++dir) {
    const float* in_w  = (const float*)d_in[3 + dir*9 + 0];
    const float* convw = (const float*)d_in[3 + dir*9 + 1];
    const float* convb = (const float*)d_in[3 + dir*9 + 2];
    const float* xprjw = (const float*)d_in[3 + dir*9 + 3];
    const float* dt_w  = (const float*)d_in[3 + dir*9 + 4];
    const float* dt_b  = (const float*)d_in[3 + dir*9 + 5];
    const float* alog  = (const float*)d_in[3 + dir*9 + 6];
    const float* Dp    = (const float*)d_in[3 + dir*9 + 7];
    const float* out_w = (const float*)d_in[3 + dir*9 + 8];

    cvt(in_w,  w_in,  2*DI*DD, stream);
    cvt(xprjw, w_xp,  80*DI,   stream);
    cvt(out_w, w_out, DD*DI,   stream);
    prep_dtw_kernel<<<(DI*64)/256, 256, 0, stream>>>(dt_w, dtwp);
    prep_A_kernel<<<(DI*DS)/256, 256, 0, stream>>>(alog, An);

    // in_proj (N=3072, K=768): 128-tile, 768 blocks
    gemm_kernel<<<dim3(32, 24), 256, 0, stream>>>(xn, DD, w_in, DD, xz, 2*DI,
                                                  2*DI, DD, nullptr, nullptr, 0,
                                                  ACT_NONE, 0, 0, dir);
    conv_silu_kernel<<<dim3(6, MM), 256, 0, stream>>>(xz, convw, convb, xc);
    // xproj (N=80, K=1536): 64-tile, 128 blocks
    gemm64_kernel<<<dim3(64, 2), 256, 0, stream>>>(xc, DI, w_xp, DI, dbc, 96,
                                                   80, DI, nullptr, nullptr, 0,
                                                   ACT_NONE, 0, 0, 0);
    // dt (N=1536, K=64): 64-tile, 1536 blocks
    gemm64_kernel<<<dim3(64, 24), 256, 0, stream>>>(dbc, 96, dtwp, 64, dtb, DI,
                                                    DI, 64, dt_b, nullptr, 0,
                                                    ACT_SOFTPLUS, 0, 0, 0);
    scan_partial<<<dim3(DI/256, NCH, NB), 256, 0, stream>>>(dtb, xc, dbc, An, Pp, Sp);
    scan_combine<<<dim3(DI*16/256, NB), 256, 0, stream>>>(Pp, Sp, h0);
    scan_final<<<dim3(DI/256, NCH, NB), 256, 0, stream>>>(dtb, xc, dbc, xz, An, Dp, h0, ybuf);
    // out_proj (N=768, K=1536): 64-tile, 768 blocks
    gemm64_kernel<<<dim3(64, 12), 256, 0, stream>>>(ybuf, DI, w_out, DI,
                                                    xfb + (dir ? DD : 0), 2*DD,
                                                    DD, DI, nullptr, nullptr, 0,
                                                    ACT_NONE, 0, dir, 0);
  }

  // mix (N=768, K=1536): 64-tile, 768 blocks
  gemm64_kernel<<<dim3(64, 12), 256, 0, stream>>>(xfb, 2*DD, w_mix, 2*DD, hbuf, DD,
                                                  DD, 2*DD, mix_b, x, DD,
                                                  ACT_NONE, 1, 0, 0);
  ln_kernel<<<MM, 256, 0, stream>>>(hbuf, ffn_ng, ffn_nb, hn);
  // ffn1 (N=3072, K=768): 128-tile, 768 blocks
  gemm_kernel<<<dim3(32, 24), 256, 0, stream>>>(hn, DD, w_f1, DD, a1, 4*DD,
                                                4*DD, DD, ffn_b1, nullptr, 0,
                                                ACT_GELU, 0, 0, 0);
  // ffn2 (N=768, K=3072): 64-tile, 768 blocks
  gemm64_kernel<<<dim3(64, 12), 256, 0, stream>>>(a1, 4*DD, w_f2, 4*DD, d_out, DD,
                                                  DD, 4*DD, ffn_b2, hbuf, DD,
                                                  ACT_NONE, 1, 0, 0);
}

// Round 6
// 755.477 us; speedup vs baseline: 5.0150x; 1.0381x over previous
//
#include <hip/hip_runtime.h>
#include <hip/hip_bf16.h>
#include <math.h>

#define NB 2
#define LL 2048
#define DD 768
#define DI 1536
#define DS 16
#define MM (NB*LL)   // 4096
#define TCH 64       // chunk length
#define NCH 32       // 2048 / TCH

typedef __hip_bfloat16 bf16;
typedef __attribute__((ext_vector_type(8))) __bf16 bf16x8;
typedef __attribute__((ext_vector_type(4))) float f32x4;

__device__ __forceinline__ float b2f(bf16 v){ return __bfloat162float(v); }
__device__ __forceinline__ bf16 f2b(float v){ return __float2bfloat16(v); }

__device__ __forceinline__ void un2(unsigned u, float& lo, float& hi){
  union {unsigned i; float f;} a, b;
  a.i = u << 16; b.i = u & 0xffff0000u;
  lo = a.f; hi = b.f;
}

__device__ __forceinline__ void async_cp16(const bf16* g, __bf16* l) {
  __builtin_amdgcn_global_load_lds((const __attribute__((address_space(1))) void*)g,
                                   (__attribute__((address_space(3))) void*)l, 16, 0, 0);
}

#define ACT_NONE 0
#define ACT_SOFTPLUS 1
#define ACT_GELU 2

__device__ __forceinline__ float apply_act(float v, int act) {
  if (act == ACT_SOFTPLUS) {
    v = (v > 15.f) ? v : log1pf(__expf(v));
  } else if (act == ACT_GELU) {
    float u = 0.7978845608028654f * (v + 0.044715f*v*v*v);
    v = 0.5f * v * (1.f + tanhf(u));
  }
  return v;
}

// 128x128 tile, BK=64: C[M,N] = A[M,K] @ B[N,K]^T (+bias) ->act (+addp)
// K must be a multiple of 64.
__global__ void gemm_kernel(const bf16* __restrict__ A, int lda,
                            const bf16* __restrict__ B, int ldb,
                            void* __restrict__ C, int ldc,
                            int N, int K,
                            const float* __restrict__ bias,
                            const float* __restrict__ addp, int ldadd,
                            int act, int f32out, int flipstore, int flipA)
{
  __shared__ __bf16 As[128*64];   // 16 KB
  __shared__ __bf16 Bs[128*64];   // 16 KB
  const int tid  = threadIdx.x;
  const int lane = tid & 63, wave = tid >> 6;
  const int m0 = blockIdx.x * 128, n0 = blockIdx.y * 128;
  const int wm = wave & 1, wn = wave >> 1;

  // staging: each wave stages 32 rows x 64 cols of A and B (8 rows per issue)
  const int srow = wave*32 + (lane >> 3);
  const int scol = (lane & 7) * 8;
  const bf16* Ag[4]; const bf16* Bg[4];
  __bf16 *AsW[4], *BsW[4];
  #pragma unroll
  for (int i = 0; i < 4; i++) {
    int ar = m0 + srow + i*8; if (flipA) ar ^= 2047;
    Ag[i] = A + (size_t)ar * lda + scol;
    int br = n0 + srow + i*8; if (br > N-1) br = N-1;
    Bg[i] = B + (size_t)br * ldb + scol;
    AsW[i] = &As[(wave*32 + i*8)*64];
    BsW[i] = &Bs[(wave*32 + i*8)*64];
  }

  f32x4 acc[4][4] = {};
  const int arow = wm*64 + (lane & 15);
  const int brow = wn*64 + (lane & 15);
  const int kg = (lane >> 4) * 8;

  for (int kb = 0; kb < K; kb += 64) {
    __syncthreads();
    #pragma unroll
    for (int i = 0; i < 4; i++) {
      async_cp16(Ag[i] + kb, AsW[i]);
      async_cp16(Bg[i] + kb, BsW[i]);
    }
    __syncthreads();
    #pragma unroll
    for (int h = 0; h < 2; h++) {
      const int kk = h*32 + kg;
      bf16x8 af[4], bfr[4];
      #pragma unroll
      for (int i = 0; i < 4; i++) af[i]  = *(const bf16x8*)&As[(arow + i*16)*64 + kk];
      #pragma unroll
      for (int j = 0; j < 4; j++) bfr[j] = *(const bf16x8*)&Bs[(brow + j*16)*64 + kk];
      #pragma unroll
      for (int i = 0; i < 4; i++)
        #pragma unroll
        for (int j = 0; j < 4; j++)
          acc[i][j] = __builtin_amdgcn_mfma_f32_16x16x32_bf16(af[i], bfr[j], acc[i][j], 0, 0, 0);
    }
  }

  bf16*  Cb = (bf16*)C;
  float* Cf = (float*)C;
  #pragma unroll
  for (int i = 0; i < 4; i++) {
    int rbase = m0 + wm*64 + i*16 + (lane >> 4)*4;
    #pragma unroll
    for (int j = 0; j < 4; j++) {
      int col = n0 + wn*64 + j*16 + (lane & 15);
      if (col >= N) continue;
      float bv = bias ? bias[col] : 0.f;
      #pragma unroll
      for (int r = 0; r < 4; r++) {
        int row = rbase + r;
        float v = apply_act(acc[i][j][r] + bv, act);
        if (addp) v += addp[(size_t)row * ldadd + col];
        int rs = flipstore ? (row ^ 2047) : row;
        if (f32out) Cf[(size_t)rs * ldc + col] = v;
        else        Cb[(size_t)rs * ldc + col] = f2b(v);
      }
    }
  }
}

// 64x64 tile, BK=64 skinny-N GEMM. K must be a multiple of 64.
__global__ void gemm64_kernel(const bf16* __restrict__ A, int lda,
                              const bf16* __restrict__ B, int ldb,
                              void* __restrict__ C, int ldc,
                              int N, int K,
                              const float* __restrict__ bias,
                              const float* __restrict__ addp, int ldadd,
                              int act, int f32out, int flipstore, int flipA)
{
  __shared__ __bf16 As[64*64];    // 8 KB
  __shared__ __bf16 Bs[64*64];    // 8 KB
  const int tid  = threadIdx.x;
  const int lane = tid & 63, wave = tid >> 6;
  const int m0 = blockIdx.x * 64, n0 = blockIdx.y * 64;
  const int wm = wave & 1, wn = wave >> 1;

  const int srow = wave*16 + (lane >> 3);
  const int scol = (lane & 7) * 8;
  const bf16* Ag[2]; const bf16* Bg[2];
  __bf16 *AsW[2], *BsW[2];
  #pragma unroll
  for (int i = 0; i < 2; i++) {
    int ar = m0 + srow + i*8; if (flipA) ar ^= 2047;
    Ag[i] = A + (size_t)ar * lda + scol;
    int br = n0 + srow + i*8; if (br > N-1) br = N-1;
    Bg[i] = B + (size_t)br * ldb + scol;
    AsW[i] = &As[(wave*16 + i*8)*64];
    BsW[i] = &Bs[(wave*16 + i*8)*64];
  }

  f32x4 acc[2][2] = {};
  const int arow = wm*32 + (lane & 15);
  const int brow = wn*32 + (lane & 15);
  const int kg = (lane >> 4) * 8;

  for (int kb = 0; kb < K; kb += 64) {
    __syncthreads();
    #pragma unroll
    for (int i = 0; i < 2; i++) {
      async_cp16(Ag[i] + kb, AsW[i]);
      async_cp16(Bg[i] + kb, BsW[i]);
    }
    __syncthreads();
    #pragma unroll
    for (int h = 0; h < 2; h++) {
      const int kk = h*32 + kg;
      bf16x8 af[2], bfr[2];
      #pragma unroll
      for (int i = 0; i < 2; i++) af[i]  = *(const bf16x8*)&As[(arow + i*16)*64 + kk];
      #pragma unroll
      for (int j = 0; j < 2; j++) bfr[j] = *(const bf16x8*)&Bs[(brow + j*16)*64 + kk];
      #pragma unroll
      for (int i = 0; i < 2; i++)
        #pragma unroll
        for (int j = 0; j < 2; j++)
          acc[i][j] = __builtin_amdgcn_mfma_f32_16x16x32_bf16(af[i], bfr[j], acc[i][j], 0, 0, 0);
    }
  }

  bf16*  Cb = (bf16*)C;
  float* Cf = (float*)C;
  #pragma unroll
  for (int i = 0; i < 2; i++) {
    int rbase = m0 + wm*32 + i*16 + (lane >> 4)*4;
    #pragma unroll
    for (int j = 0; j < 2; j++) {
      int col = n0 + wn*32 + j*16 + (lane & 15);
      if (col >= N) continue;
      float bv = bias ? bias[col] : 0.f;
      #pragma unroll
      for (int r = 0; r < 4; r++) {
        int row = rbase + r;
        float v = apply_act(acc[i][j][r] + bv, act);
        if (addp) v += addp[(size_t)row * ldadd + col];
        int rs = flipstore ? (row ^ 2047) : row;
        if (f32out) Cf[(size_t)rs * ldc + col] = v;
        else        Cb[(size_t)rs * ldc + col] = f2b(v);
      }
    }
  }
}

// LayerNorm over D=768; fp32 in, bf16 out
__global__ void ln_kernel(const float* __restrict__ x, const float* __restrict__ g,
                          const float* __restrict__ b, bf16* __restrict__ out)
{
  const int row = blockIdx.x;
  const int tid = threadIdx.x;
  const float* xr = x + (size_t)row * DD;
  float v[3], s = 0.f, s2 = 0.f;
  #pragma unroll
  for (int i = 0; i < 3; i++) {
    float f = xr[tid + i*256];
    v[i] = f; s += f; s2 += f*f;
  }
  #pragma unroll
  for (int o = 32; o > 0; o >>= 1) { s += __shfl_down(s, o, 64); s2 += __shfl_down(s2, o, 64); }
  __shared__ float ps[4], ps2[4];
  int wave = tid >> 6;
  if ((tid & 63) == 0) { ps[wave] = s; ps2[wave] = s2; }
  __syncthreads();
  s = ps[0]+ps[1]+ps[2]+ps[3]; s2 = ps2[0]+ps2[1]+ps2[2]+ps2[3];
  float mu = s * (1.f/DD);
  float var = s2 * (1.f/DD) - mu*mu;
  float rs = rsqrtf(var + 1e-5f);
  #pragma unroll
  for (int i = 0; i < 3; i++) {
    int c = tid + i*256;
    float o = (v[i] - mu) * rs * g[c] + b[c];
    out[(size_t)row * DD + c] = f2b(o);
  }
}

// causal depthwise conv (K=4) + silu over the xc half of xz
__global__ void conv_silu_kernel(const bf16* __restrict__ xz, const float* __restrict__ cw,
                                 const float* __restrict__ cb, bf16* __restrict__ xc)
{
  int d = blockIdx.x * 256 + threadIdx.x;
  int row = blockIdx.y;
  int b = row >> 11, t = row & 2047;
  float acc = cb[d];
  float w0 = cw[d*4+0], w1 = cw[d*4+1], w2 = cw[d*4+2], w3 = cw[d*4+3];
  const bf16* base = xz + (size_t)(b*2048) * 3072 + d;
  if (t >= 3) acc += b2f(base[(size_t)(t-3)*3072]) * w0;
  if (t >= 2) acc += b2f(base[(size_t)(t-2)*3072]) * w1;
  if (t >= 1) acc += b2f(base[(size_t)(t-1)*3072]) * w2;
  acc += b2f(base[(size_t)t*3072]) * w3;
  float y = acc / (1.f + __expf(-acc));
  xc[(size_t)row * DI + d] = f2b(y);
}

// fused head weight conversion: mix_w, ffn_w1, ffn_w2
#define SZ_MIX (2*DD*DD)
#define SZ_F1  (4*DD*DD)
__global__ void prep_shared_kernel(const float* __restrict__ mix_w,
                                   const float* __restrict__ f1,
                                   const float* __restrict__ f2,
                                   bf16* __restrict__ w_mix,
                                   bf16* __restrict__ w_f1,
                                   bf16* __restrict__ w_f2)
{
  int i = blockIdx.x * 256 + threadIdx.x;
  if (i < SZ_MIX) { w_mix[i] = f2b(mix_w[i]); return; }
  i -= SZ_MIX;
  if (i < SZ_F1) { w_f1[i] = f2b(f1[i]); return; }
  i -= SZ_F1;
  w_f2[i] = f2b(f2[i]);
}

// fused per-dir prep: in_w cvt, xproj cvt, out_w cvt, dt_w pad-cvt, A table
#define SZ_INW (2*DI*DD)
#define SZ_XP  (80*DI)
#define SZ_OUT (DD*DI)
#define SZ_DTW (DI*64)
__global__ void prep_dir_kernel(const float* __restrict__ in_w,
                                const float* __restrict__ xprjw,
                                const float* __restrict__ out_w,
                                const float* __restrict__ dtw,
                                const float* __restrict__ alog,
                                bf16* __restrict__ w_in, bf16* __restrict__ w_xp,
                                bf16* __restrict__ w_out, bf16* __restrict__ dtwp,
                                float* __restrict__ An)
{
  int i = blockIdx.x * 256 + threadIdx.x;
  if (i < SZ_INW) { w_in[i] = f2b(in_w[i]); return; }
  i -= SZ_INW;
  if (i < SZ_XP) { w_xp[i] = f2b(xprjw[i]); return; }
  i -= SZ_XP;
  if (i < SZ_OUT) { w_out[i] = f2b(out_w[i]); return; }
  i -= SZ_OUT;
  if (i < SZ_DTW) {
    int r = i >> 6, c = i & 63;
    dtwp[i] = (c < 48) ? f2b(dtw[r*48 + c]) : f2b(0.f);
    return;
  }
  i -= SZ_DTW;
  { int d = i >> 4, s = i & 15; An[s*DI + d] = -__expf(alog[i]); }
}

// ---- chunked parallel scan ----
__global__ void scan_partial(const bf16* __restrict__ dt, const bf16* __restrict__ xc,
                             const bf16* __restrict__ dbc, const float* __restrict__ An,
                             float* __restrict__ Pp, float* __restrict__ Sp)
{
  const int tid = threadIdx.x;
  const int d = blockIdx.x * 256 + tid;
  const int c = blockIdx.y, b = blockIdx.z;
  const int rowbase = b*2048 + c*TCH;
  __shared__ unsigned bcs[TCH*16];
  for (int i = tid; i < TCH*16; i += 256) {
    int r = i >> 4, dw = i & 15;
    bcs[i] = ((const unsigned*)(dbc + (size_t)(rowbase + r)*96 + 48))[dw];
  }
  __syncthreads();
  float A[16], P[16], g[16];
  #pragma unroll
  for (int s = 0; s < 16; s++) { A[s] = An[s*DI + d]; P[s] = 1.f; g[s] = 0.f; }
  float dtv = b2f(dt[(size_t)rowbase*DI + d]);
  float xv  = b2f(xc[(size_t)rowbase*DI + d]);
  for (int t = 0; t < TCH; t++) {
    float dtn = 0.f, xvn = 0.f;
    if (t + 1 < TCH) {
      dtn = b2f(dt[(size_t)(rowbase+t+1)*DI + d]);
      xvn = b2f(xc[(size_t)(rowbase+t+1)*DI + d]);
    }
    unsigned ub[8];
    *(uint4*)&ub[0] = *(const uint4*)&bcs[t*16];
    *(uint4*)&ub[4] = *(const uint4*)&bcs[t*16 + 4];
    float Bv[16];
    #pragma unroll
    for (int k = 0; k < 8; k++) un2(ub[k], Bv[2*k], Bv[2*k+1]);
    float u = dtv * xv;
    #pragma unroll
    for (int s = 0; s < 16; s++) {
      float dA = __expf(dtv * A[s]);
      P[s] *= dA;
      g[s] = dA * g[s] + u * Bv[s];
    }
    dtv = dtn; xv = xvn;
  }
  size_t base = ((size_t)(b*NCH + c)*DI + d) * 16;
  #pragma unroll
  for (int s = 0; s < 16; s++) { Pp[base+s] = P[s]; Sp[base+s] = g[s]; }
}

__global__ void scan_combine(const float* __restrict__ Pp, const float* __restrict__ Sp,
                             float* __restrict__ h0)
{
  const int j = blockIdx.x * 256 + threadIdx.x;
  const int b = blockIdx.y;
  float h = 0.f;
  for (int c = 0; c < NCH; c++) {
    size_t idx = ((size_t)(b*NCH + c)*DI)*16 + j;
    h0[idx] = h;
    h = Pp[idx]*h + Sp[idx];
  }
}

__global__ void scan_final(const bf16* __restrict__ dt, const bf16* __restrict__ xc,
                           const bf16* __restrict__ dbc, const bf16* __restrict__ xz,
                           const float* __restrict__ An, const float* __restrict__ Dp,
                           const float* __restrict__ h0, bf16* __restrict__ yout)
{
  const int tid = threadIdx.x;
  const int d = blockIdx.x * 256 + tid;
  const int c = blockIdx.y, b = blockIdx.z;
  const int rowbase = b*2048 + c*TCH;
  __shared__ unsigned bcs[TCH*16];
  for (int i = tid; i < TCH*16; i += 256) {
    int r = i >> 4, dw = i & 15;
    bcs[i] = ((const unsigned*)(dbc + (size_t)(rowbase + r)*96 + 48))[dw];
  }
  __syncthreads();
  float A[16], h[16];
  size_t hbase = ((size_t)(b*NCH + c)*DI + d) * 16;
  #pragma unroll
  for (int s = 0; s < 16; s++) { A[s] = An[s*DI + d]; h[s] = h0[hbase+s]; }
  const float Dd = Dp[d];
  float dtv = b2f(dt[(size_t)rowbase*DI + d]);
  float xv  = b2f(xc[(size_t)rowbase*DI + d]);
  for (int t = 0; t < TCH; t++) {
    const int row = rowbase + t;
    float dtn = 0.f, xvn = 0.f;
    if (t + 1 < TCH) {
      dtn = b2f(dt[(size_t)(row+1)*DI + d]);
      xvn = b2f(xc[(size_t)(row+1)*DI + d]);
    }
    unsigned ub[8], uc[8];
    *(uint4*)&ub[0] = *(const uint4*)&bcs[t*16];
    *(uint4*)&ub[4] = *(const uint4*)&bcs[t*16 + 4];
    *(uint4*)&uc[0] = *(const uint4*)&bcs[t*16 + 8];
    *(uint4*)&uc[4] = *(const uint4*)&bcs[t*16 + 12];
    float Bv[16], Cv[16];
    #pragma unroll
    for (int k = 0; k < 8; k++) { un2(ub[k], Bv[2*k], Bv[2*k+1]); un2(uc[k], Cv[2*k], Cv[2*k+1]); }
    float u = dtv * xv;
    float y = 0.f;
    #pragma unroll
    for (int s = 0; s < 16; s++) {
      float dA = __expf(dtv * A[s]);
      h[s] = dA * h[s] + u * Bv[s];
      y += h[s] * Cv[s];
    }
    float zv = b2f(xz[(size_t)row*3072 + 1536 + d]);
    float yg = (y + xv * Dd) * (zv / (1.f + __expf(-zv)));
    yout[(size_t)row*DI + d] = f2b(yg);
    dtv = dtn; xv = xvn;
  }
}

extern "C" void kernel_launch(void* const* d_in, const int* in_sizes, int n_in,
                              void* d_out, int out_size, void* d_ws, size_t ws_size,
                              hipStream_t stream)
{
  const float* x      = (const float*)d_in[0];
  const float* norm_g = (const float*)d_in[1];
  const float* norm_b = (const float*)d_in[2];
  const float* mix_w  = (const float*)d_in[21];
  const float* mix_b  = (const float*)d_in[22];
  const float* ffn_w1 = (const float*)d_in[23];
  const float* ffn_b1 = (const float*)d_in[24];
  const float* ffn_w2 = (const float*)d_in[25];
  const float* ffn_b2 = (const float*)d_in[26];
  const float* ffn_ng = (const float*)d_in[27];
  const float* ffn_nb = (const float*)d_in[28];

  size_t o = 0;
  char* wsb = (char*)d_ws;
  auto nxt = [&](size_t bytes) -> char* {
    char* p = wsb + o; o += (bytes + 255) & ~(size_t)255; return p;
  };
  float* An   = (float*)nxt((size_t)DI*DS*4);
  bf16*  dtwp = (bf16*) nxt((size_t)DI*64*2);
  bf16*  w_in = (bf16*) nxt((size_t)2*DI*DD*2);
  bf16*  w_xp = (bf16*) nxt((size_t)80*DI*2);
  bf16*  w_out= (bf16*) nxt((size_t)DD*DI*2);
  bf16*  w_mix= (bf16*) nxt((size_t)DD*2*DD*2);
  bf16*  w_f1 = (bf16*) nxt((size_t)4*DD*DD*2);
  bf16*  w_f2 = (bf16*) nxt((size_t)DD*4*DD*2);
  bf16*  dbc  = (bf16*) nxt((size_t)MM*96*2);
  bf16*  xn   = (bf16*) nxt((size_t)MM*DD*2);       // reused as hn
  bf16*  xc   = (bf16*) nxt((size_t)MM*DI*2);       // ybuf aliases this
  bf16*  dtb  = (bf16*) nxt((size_t)MM*DI*2);
  bf16*  xfb  = (bf16*) nxt((size_t)MM*DI*2);
  float* Pp   = (float*)nxt((size_t)NB*NCH*DI*16*4);
  float* Sp   = (float*)nxt((size_t)NB*NCH*DI*16*4);
  float* h0   = (float*)nxt((size_t)NB*NCH*DI*16*4);
  bf16*  xz   = (bf16*) nxt((size_t)MM*2*DI*2);     // reused as a1
  bf16*  ybuf = xc;
  bf16*  hn   = xn;
  bf16*  a1   = xz;
  float* hbuf = Pp;   // dead scan scratch by the time mix runs

  prep_shared_kernel<<<(SZ_MIX + SZ_F1 + SZ_F1 + 255)/256, 256, 0, stream>>>(
      mix_w, ffn_w1, ffn_w2, w_mix, w_f1, w_f2);

  ln_kernel<<<MM, 256, 0, stream>>>(x, norm_g, norm_b, xn);

  for (int dir = 0; dir < 2; ++dir) {
    const float* in_w  = (const float*)d_in[3 + dir*9 + 0];
    const float* convw = (const float*)d_in[3 + dir*9 + 1];
    const float* convb = (const float*)d_in[3 + dir*9 + 2];
    const float* xprjw = (const float*)d_in[3 + dir*9 + 3];
    const float* dt_w  = (const float*)d_in[3 + dir*9 + 4];
    const float* dt_b  = (const float*)d_in[3 + dir*9 + 5];
    const float* alog  = (const float*)d_in[3 + dir*9 + 6];
    const float* Dp    = (const float*)d_in[3 + dir*9 + 7];
    const float* out_w = (const float*)d_in[3 + dir*9 + 8];

    prep_dir_kernel<<<(SZ_INW + SZ_XP + SZ_OUT + SZ_DTW + DI*16 + 255)/256, 256, 0, stream>>>(
        in_w, xprjw, out_w, dt_w, alog, w_in, w_xp, w_out, dtwp, An);

    // in_proj (N=3072, K=768): 128-tile BK=64, 768 blocks
    gemm_kernel<<<dim3(32, 24), 256, 0, stream>>>(xn, DD, w_in, DD, xz, 2*DI,
                                                  2*DI, DD, nullptr, nullptr, 0,
                                                  ACT_NONE, 0, 0, dir);
    conv_silu_kernel<<<dim3(6, MM), 256, 0, stream>>>(xz, convw, convb, xc);
    // xproj (N=80, K=1536): 64-tile, 128 blocks
    gemm64_kernel<<<dim3(64, 2), 256, 0, stream>>>(xc, DI, w_xp, DI, dbc, 96,
                                                   80, DI, nullptr, nullptr, 0,
                                                   ACT_NONE, 0, 0, 0);
    // dt (N=1536, K=64): 64-tile single iter, 1536 blocks
    gemm64_kernel<<<dim3(64, 24), 256, 0, stream>>>(dbc, 96, dtwp, 64, dtb, DI,
                                                    DI, 64, dt_b, nullptr, 0,
                                                    ACT_SOFTPLUS, 0, 0, 0);
    scan_partial<<<dim3(DI/256, NCH, NB), 256, 0, stream>>>(dtb, xc, dbc, An, Pp, Sp);
    scan_combine<<<dim3(DI*16/256, NB), 256, 0, stream>>>(Pp, Sp, h0);
    scan_final<<<dim3(DI/256, NCH, NB), 256, 0, stream>>>(dtb, xc, dbc, xz, An, Dp, h0, ybuf);
    // out_proj (N=768, K=1536): 64-tile, 768 blocks
    gemm64_kernel<<<dim3(64, 12), 256, 0, stream>>>(ybuf, DI, w_out, DI,
                                                    xfb + (dir ? DD : 0), 2*DD,
                                                    DD, DI, nullptr, nullptr, 0,
                                                    ACT_NONE, 0, dir, 0);
  }

  // mix (N=768, K=1536): 64-tile, 768 blocks
  gemm64_kernel<<<dim3(64, 12), 256, 0, stream>>>(xfb, 2*DD, w_mix, 2*DD, hbuf, DD,
                                                  DD, 2*DD, mix_b, x, DD,
                                                  ACT_NONE, 1, 0, 0);
  ln_kernel<<<MM, 256, 0, stream>>>(hbuf, ffn_ng, ffn_nb, hn);
  // ffn1 (N=3072, K=768): 128-tile BK=64, 768 blocks
  gemm_kernel<<<dim3(32, 24), 256, 0, stream>>>(hn, DD, w_f1, DD, a1, 4*DD,
                                                4*DD, DD, ffn_b1, nullptr, 0,
                                                ACT_GELU, 0, 0, 0);
  // ffn2 (N=768, K=3072): 64-tile, 768 blocks
  gemm64_kernel<<<dim3(64, 12), 256, 0, stream>>>(a1, 4*DD, w_f2, 4*DD, d_out, DD,
                                                  DD, 4*DD, ffn_b2, hbuf, DD,
                                                  ACT_NONE, 1, 0, 0);
}